// Round 5
// baseline (33663.083 us; speedup 1.0000x reference)
//
#include <hip/hip_runtime.h>

// GeodesicStateBlock: GRU-style scan (B=16,S=2048,D=512) + LayerNorm.
// Identity: deformed = points + (states - points) = states, so out = LN(states).
//
// Round-8 structure: TOKEN-IN-DWORD self-validating exchange.
//  - h and r*h are exchanged as packed dwords: (token<<16) | f16_bits.
//    Aligned 4B stores/loads are single-copy atomic, so every dword
//    self-validates: consumer loads all fragments (sc0 sc1 = LLC-coherent),
//    XORs with token<<16 (high16==0 <=> valid; low16 = payload in place),
//    OR-reduces, retries until ALL match. Stale data is structurally
//    impossible -- no producer drain, no ready-flag, no poll->load RT, no
//    memory-ordering assumptions. (Round-7's separate-flag fusion was racy:
//    flag loads serviced late under contention, data loads early.)
//  - Tokens: h_t carries token t (memset 0 == h_0 = 0, token 0). r*h at step
//    t carries token t+1. Monotonic, no wraparound (t < 2048 << 65536).
//  - WAR/deadlock chain: h(t+1) stores (phase B) are gated on rh-tokens(t+1)
//    from all blocks (proves waves 0/1 everywhere finished reading h(t)) AND
//    on zdone[32] >= t+1 (z-waves publish after validating their h(t) read;
//    reader-done signals are one-directional and race-free). rh(t+2) stores
//    (phase A of t+2) are gated on h-tokens(t+2), which requires every
//    block's phase B of t+1, which follows its rh(t+1) read. No reader can
//    be overtaken => no deadlock, no torn data.
//  - Unpack: 1 v_perm per f16-pair. Token check: ~2 VALU/dword, paid while
//    loads drain. No vmcnt drains anywhere on the critical path.

typedef _Float16 half8 __attribute__((ext_vector_type(8)));
typedef _Float16 half4 __attribute__((ext_vector_type(4)));
typedef float floatx4 __attribute__((ext_vector_type(4)));
typedef int int4v __attribute__((ext_vector_type(4)));

#define NBLK 16
#define TPB 256
#define S_LEN 2048

// ws layout (bytes)
#define SZ_WPK (96ull * 16 * 64 * 8 * 2)  // 1,572,864 (96 tiles x 16 KB)
#define OFF_WHPK 0ull
#define OFF_WXPK (OFF_WHPK + SZ_WPK)
#define OFF_HBUF (OFF_WXPK + SZ_WPK)   // 32 KB: h2[16][512] dwords (zeroed)
#define OFF_CNT (OFF_HBUF + 32768ull)  // 16 KB: zdone[0..31] (zeroed)
#define OFF_RH (OFF_CNT + 16384ull)    // 32 KB: rh2[16][512] dwords (zeroed)
#define OFF_XGT (OFF_RH + 32768ull)    // 2048*96*256*2 = 100,663,296 B

__device__ __forceinline__ float sigmoid_f(float x) {
  return 1.f / (1.f + __expf(-x));
}
__device__ __forceinline__ float tanh_f(float x) {
  x = fminf(15.f, fmaxf(-15.f, x));
  float e = __expf(2.f * x);
  return (e - 1.f) / (e + 1.f);
}

// ---- LLC-coherent (sc0 sc1) ops ----
// 16 dwordx4 loads, fragments kc=0..7 (byte offsets kc*128 + {0,16}). No wait.
__device__ __forceinline__ void ld16a(const unsigned* p, int4v (&d)[16]) {
  asm volatile(
      "global_load_dwordx4 %0,  %16, off sc0 sc1\n\t"
      "global_load_dwordx4 %1,  %16, off offset:16 sc0 sc1\n\t"
      "global_load_dwordx4 %2,  %16, off offset:128 sc0 sc1\n\t"
      "global_load_dwordx4 %3,  %16, off offset:144 sc0 sc1\n\t"
      "global_load_dwordx4 %4,  %16, off offset:256 sc0 sc1\n\t"
      "global_load_dwordx4 %5,  %16, off offset:272 sc0 sc1\n\t"
      "global_load_dwordx4 %6,  %16, off offset:384 sc0 sc1\n\t"
      "global_load_dwordx4 %7,  %16, off offset:400 sc0 sc1\n\t"
      "global_load_dwordx4 %8,  %16, off offset:512 sc0 sc1\n\t"
      "global_load_dwordx4 %9,  %16, off offset:528 sc0 sc1\n\t"
      "global_load_dwordx4 %10, %16, off offset:640 sc0 sc1\n\t"
      "global_load_dwordx4 %11, %16, off offset:656 sc0 sc1\n\t"
      "global_load_dwordx4 %12, %16, off offset:768 sc0 sc1\n\t"
      "global_load_dwordx4 %13, %16, off offset:784 sc0 sc1\n\t"
      "global_load_dwordx4 %14, %16, off offset:896 sc0 sc1\n\t"
      "global_load_dwordx4 %15, %16, off offset:912 sc0 sc1"
      : "=&v"(d[0]), "=&v"(d[1]), "=&v"(d[2]), "=&v"(d[3]), "=&v"(d[4]),
        "=&v"(d[5]), "=&v"(d[6]), "=&v"(d[7]), "=&v"(d[8]), "=&v"(d[9]),
        "=&v"(d[10]), "=&v"(d[11]), "=&v"(d[12]), "=&v"(d[13]), "=&v"(d[14]),
        "=&v"(d[15])
      : "v"(p)
      : "memory");
}
// fragments kc=8..15 (byte offsets 1024..1936) + drain of ALL outstanding.
__device__ __forceinline__ void ld16b(const unsigned* p, int4v (&d)[16]) {
  asm volatile(
      "global_load_dwordx4 %0,  %16, off offset:1024 sc0 sc1\n\t"
      "global_load_dwordx4 %1,  %16, off offset:1040 sc0 sc1\n\t"
      "global_load_dwordx4 %2,  %16, off offset:1152 sc0 sc1\n\t"
      "global_load_dwordx4 %3,  %16, off offset:1168 sc0 sc1\n\t"
      "global_load_dwordx4 %4,  %16, off offset:1280 sc0 sc1\n\t"
      "global_load_dwordx4 %5,  %16, off offset:1296 sc0 sc1\n\t"
      "global_load_dwordx4 %6,  %16, off offset:1408 sc0 sc1\n\t"
      "global_load_dwordx4 %7,  %16, off offset:1424 sc0 sc1\n\t"
      "global_load_dwordx4 %8,  %16, off offset:1536 sc0 sc1\n\t"
      "global_load_dwordx4 %9,  %16, off offset:1552 sc0 sc1\n\t"
      "global_load_dwordx4 %10, %16, off offset:1664 sc0 sc1\n\t"
      "global_load_dwordx4 %11, %16, off offset:1680 sc0 sc1\n\t"
      "global_load_dwordx4 %12, %16, off offset:1792 sc0 sc1\n\t"
      "global_load_dwordx4 %13, %16, off offset:1808 sc0 sc1\n\t"
      "global_load_dwordx4 %14, %16, off offset:1920 sc0 sc1\n\t"
      "global_load_dwordx4 %15, %16, off offset:1936 sc0 sc1\n\t"
      "s_waitcnt vmcnt(0)"
      : "=&v"(d[0]), "=&v"(d[1]), "=&v"(d[2]), "=&v"(d[3]), "=&v"(d[4]),
        "=&v"(d[5]), "=&v"(d[6]), "=&v"(d[7]), "=&v"(d[8]), "=&v"(d[9]),
        "=&v"(d[10]), "=&v"(d[11]), "=&v"(d[12]), "=&v"(d[13]), "=&v"(d[14]),
        "=&v"(d[15])
      : "v"(p)
      : "memory");
}
// same as ld16b + one zdone dword, then drain.
__device__ __forceinline__ void ld16bz(const unsigned* p, const unsigned* zp,
                                       int4v (&d)[16], unsigned& zd) {
  asm volatile(
      "global_load_dwordx4 %0,  %17, off offset:1024 sc0 sc1\n\t"
      "global_load_dwordx4 %1,  %17, off offset:1040 sc0 sc1\n\t"
      "global_load_dwordx4 %2,  %17, off offset:1152 sc0 sc1\n\t"
      "global_load_dwordx4 %3,  %17, off offset:1168 sc0 sc1\n\t"
      "global_load_dwordx4 %4,  %17, off offset:1280 sc0 sc1\n\t"
      "global_load_dwordx4 %5,  %17, off offset:1296 sc0 sc1\n\t"
      "global_load_dwordx4 %6,  %17, off offset:1408 sc0 sc1\n\t"
      "global_load_dwordx4 %7,  %17, off offset:1424 sc0 sc1\n\t"
      "global_load_dwordx4 %8,  %17, off offset:1536 sc0 sc1\n\t"
      "global_load_dwordx4 %9,  %17, off offset:1552 sc0 sc1\n\t"
      "global_load_dwordx4 %10, %17, off offset:1664 sc0 sc1\n\t"
      "global_load_dwordx4 %11, %17, off offset:1680 sc0 sc1\n\t"
      "global_load_dwordx4 %12, %17, off offset:1792 sc0 sc1\n\t"
      "global_load_dwordx4 %13, %17, off offset:1808 sc0 sc1\n\t"
      "global_load_dwordx4 %14, %17, off offset:1920 sc0 sc1\n\t"
      "global_load_dwordx4 %15, %17, off offset:1936 sc0 sc1\n\t"
      "global_load_dword   %16, %18, off sc0 sc1\n\t"
      "s_waitcnt vmcnt(0)"
      : "=&v"(d[0]), "=&v"(d[1]), "=&v"(d[2]), "=&v"(d[3]), "=&v"(d[4]),
        "=&v"(d[5]), "=&v"(d[6]), "=&v"(d[7]), "=&v"(d[8]), "=&v"(d[9]),
        "=&v"(d[10]), "=&v"(d[11]), "=&v"(d[12]), "=&v"(d[13]), "=&v"(d[14]),
        "=&v"(d[15]), "=&v"(zd)
      : "v"(p), "v"(zp)
      : "memory");
}
__device__ __forceinline__ void st_dw(unsigned* p, unsigned v) {
  asm volatile("global_store_dword %0, %1, off sc0 sc1" ::"v"(p), "v"(v)
               : "memory");
}
// pack low16 of (p0,p1) -> one dword (p0 low, p1 high)
__device__ __forceinline__ unsigned pk2(unsigned p1, unsigned p0) {
  return __builtin_amdgcn_perm(p1, p0, 0x05040100u);
}
// 8 validated dwords (2 x int4v) -> half8 fragment (payload low16s)
__device__ __forceinline__ half8 unpk(int4v lo, int4v hi) {
  int4v f;
  f[0] = (int)pk2((unsigned)lo[1], (unsigned)lo[0]);
  f[1] = (int)pk2((unsigned)lo[3], (unsigned)lo[2]);
  f[2] = (int)pk2((unsigned)hi[1], (unsigned)hi[0]);
  f[3] = (int)pk2((unsigned)hi[3], (unsigned)hi[2]);
  return __builtin_bit_cast(half8, f);
}

// ---- pack weights into MFMA B-fragment order ----
// Whpk/Wxpk: [96 tiles][16 kc][64 lanes][8 f16]; tiles 0..63 gate, 64..95 cand.
// B-frag: lane holds B[k = kc*32 + (lane>>4)*8 + jj][n = lane&15].
__global__ void pack_kernel(const float* __restrict__ Wg,
                            const float* __restrict__ Wc,
                            _Float16* __restrict__ Whpk,
                            _Float16* __restrict__ Wxpk) {
  int unit = blockIdx.x * 4 + (threadIdx.x >> 6);  // 0..3071
  int lane = threadIdx.x & 63;
  int set = (unit >= 1536) ? 1 : 0;  // 0: h-part (rows 512+), 1: x-part
  int rem = unit - set * 1536;
  int tile = rem >> 4, kc = rem & 15;
  int kb = kc * 32 + ((lane >> 4) << 3);
  int n = lane & 15;
  int row0 = set ? 0 : 512;
  half8 w;
  if (tile < 64) {
    int col = tile * 16 + n;
#pragma unroll
    for (int jj = 0; jj < 8; ++jj)
      w[jj] = (_Float16)Wg[(size_t)(row0 + kb + jj) * 1024 + col];
  } else {
    int col = (tile - 64) * 16 + n;
#pragma unroll
    for (int jj = 0; jj < 8; ++jj)
      w[jj] = (_Float16)Wc[(size_t)(row0 + kb + jj) * 512 + col];
  }
  _Float16* dst = set ? Wxpk : Whpk;
  *(half8*)(dst + ((size_t)rem * 64 + lane) * 8) = w;
}

// ---- XGT = points @ W_x + bias, all steps; layout [t][tile][c16][b16] ----
__global__ __launch_bounds__(TPB) void xgemm_kernel(
    const float* __restrict__ points, const float* __restrict__ b_gate,
    const float* __restrict__ b_cand, const _Float16* __restrict__ Wxpk,
    _Float16* __restrict__ xgt) {
  __shared__ _Float16 x_lds[16][520];
  const int tid = threadIdx.x;
  const int wave = tid >> 6, lane = tid & 63;
  const int ln15 = lane & 15, q = lane >> 4;
  const int t = blockIdx.x;
  const int m = tid & 15, ch = tid >> 4;

  // stage x_t (f32 -> f16)
  const float* xp = points + ((size_t)m * S_LEN + t) * 512 + ch * 32;
#pragma unroll
  for (int u = 0; u < 4; ++u) {
    float4 f0 = ((const float4*)xp)[2 * u];
    float4 f1 = ((const float4*)xp)[2 * u + 1];
    half8 hv;
    hv[0] = (_Float16)f0.x; hv[1] = (_Float16)f0.y;
    hv[2] = (_Float16)f0.z; hv[3] = (_Float16)f0.w;
    hv[4] = (_Float16)f1.x; hv[5] = (_Float16)f1.y;
    hv[6] = (_Float16)f1.z; hv[7] = (_Float16)f1.w;
    *(half8*)&x_lds[m][ch * 32 + u * 8] = hv;
  }
  __syncthreads();

  for (int tile = wave; tile < 96; tile += 4) {
    const _Float16* W = Wxpk + (size_t)tile * 8192;
    floatx4 a0 = {0.f, 0.f, 0.f, 0.f}, a1 = {0.f, 0.f, 0.f, 0.f};
#pragma unroll
    for (int kc = 0; kc < 16; kc += 2) {
      a0 = __builtin_amdgcn_mfma_f32_16x16x32_f16(
          *(const half8*)&x_lds[ln15][kc * 32 + q * 8],
          *(const half8*)(W + ((size_t)kc * 64 + lane) * 8), a0, 0, 0, 0);
      a1 = __builtin_amdgcn_mfma_f32_16x16x32_f16(
          *(const half8*)&x_lds[ln15][(kc + 1) * 32 + q * 8],
          *(const half8*)(W + ((size_t)(kc + 1) * 64 + lane) * 8), a1, 0, 0, 0);
    }
    float bias = (tile < 64) ? b_gate[tile * 16 + ln15]
                             : b_cand[(tile - 64) * 16 + ln15];
    half4 o;
#pragma unroll
    for (int i = 0; i < 4; ++i) o[i] = (_Float16)(a0[i] + a1[i] + bias);
    *(half4*)(xgt + (((size_t)t * 96 + tile) * 16 + ln15) * 16 + q * 4) = o;
  }
}

// ---- serial recurrence: 16 persistent blocks, register-resident weights ----
__global__ __launch_bounds__(TPB, 1) void rec_kernel(
    const _Float16* __restrict__ Whpk, const _Float16* __restrict__ xgt,
    unsigned* __restrict__ h2, unsigned* __restrict__ rh2,
    unsigned* __restrict__ zdone, float* __restrict__ out) {
  __shared__ float z_lds[2][16][36];

  const int tid = threadIdx.x;
  const int wave = tid >> 6, lane = tid & 63;
  const int ln15 = lane & 15, q = lane >> 4;
  const int j = blockIdx.x;

  // wave -> tiles: waves 0,1 gate-r tiles 2j,2j+1 (cols 32j..32j+31) + cand
  // tiles 64+2j,65+2j; waves 2,3 gate-z tiles 32+2j,33+2j.
  const int twA = (wave < 2) ? (2 * j + wave) : (32 + 2 * j + (wave - 2));
  const int twB = 64 + 2 * j + (wave & 1);
  const int colA = 32 * j + 16 * (wave & 1) + ln15;

  // weights -> registers (tile stride 8192 f16; kc stride 512 f16)
  half8 wA[16], wB[16];
  {
    const _Float16* sA = Whpk + (size_t)twA * 8192 + lane * 8;
#pragma unroll
    for (int kc = 0; kc < 16; ++kc) wA[kc] = *(const half8*)(sA + kc * 512);
  }
  if (wave < 2) {
    const _Float16* sB = Whpk + (size_t)twB * 8192 + lane * 8;
#pragma unroll
    for (int kc = 0; kc < 16; ++kc) wB[kc] = *(const half8*)(sB + kc * 512);
  }

  const unsigned* h2rd = h2 + ln15 * 512 + q * 8;    // A-frag base (dwords)
  const unsigned* rh2rd = rh2 + ln15 * 512 + q * 8;
  unsigned* rh2wr = rh2 + (q * 4) * 512 + colA;      // + i*512
  unsigned* h2wr = h2 + (q * 4) * 512 + colA;        // + i*512
  const unsigned* zdp = zdone + (lane & 31);

  // xgt operand pointers; per-t stride = 96*16*16 = 24576 f16.
  const _Float16* xga_p = xgt + ((size_t)twA * 16 + ln15) * 16 + q * 4;
  const _Float16* xcb_p = xgt + ((size_t)twB * 16 + ln15) * 16 + q * 4;
  half4 xga = *(const half4*)xga_p;
  half4 xcb = {0, 0, 0, 0};
  if (wave < 2) xcb = *(const half4*)xcb_p;

  float hreg[4] = {0.f, 0.f, 0.f, 0.f};  // h[q*4+i][colA] (waves 0-1)

  for (int t = 0; t < S_LEN; ++t) {
    const size_t pn = (size_t)((t + 1 < S_LEN) ? t + 1 : t) * 24576;
    const unsigned tok1 = (unsigned)t + 1u;
    const unsigned tokhi1 = tok1 << 16;

    // ---- phase A: validated h_t read (token == t), all 4 waves ----
    int4v dlo[16], dhi[16];
    {
      const unsigned tokpat = ((unsigned)t) << 16;
      for (;;) {
        ld16a(h2rd, dlo);
        ld16b(h2rd, dhi);
        unsigned acc = 0;
#pragma unroll
        for (int u = 0; u < 16; ++u) {
#pragma unroll
          for (int c = 0; c < 4; ++c) {
            acc |= (((unsigned)dlo[u][c]) ^ tokpat);
            acc |= (((unsigned)dhi[u][c]) ^ tokpat);
          }
        }
        if (__all((int)((acc >> 16) == 0u))) break;
      }
    }
    floatx4 a0 = {0.f, 0.f, 0.f, 0.f}, a1 = {0.f, 0.f, 0.f, 0.f};
#pragma unroll
    for (int kc = 0; kc < 8; kc += 2) {
      a0 = __builtin_amdgcn_mfma_f32_16x16x32_f16(
          unpk(dlo[2 * kc], dlo[2 * kc + 1]), wA[kc], a0, 0, 0, 0);
      a1 = __builtin_amdgcn_mfma_f32_16x16x32_f16(
          unpk(dlo[2 * kc + 2], dlo[2 * kc + 3]), wA[kc + 1], a1, 0, 0, 0);
    }
#pragma unroll
    for (int kc = 8; kc < 16; kc += 2) {
      a0 = __builtin_amdgcn_mfma_f32_16x16x32_f16(
          unpk(dhi[2 * (kc - 8)], dhi[2 * (kc - 8) + 1]), wA[kc], a0, 0, 0, 0);
      a1 = __builtin_amdgcn_mfma_f32_16x16x32_f16(
          unpk(dhi[2 * (kc - 8) + 2], dhi[2 * (kc - 8) + 3]), wA[kc + 1], a1,
          0, 0, 0);
    }

    if (wave < 2) {  // r-cols: publish r*h as token-dwords (no drain needed)
      half4 xga_nx = *(const half4*)(xga_p + pn);
#pragma unroll
      for (int i = 0; i < 4; ++i) {
        float r = sigmoid_f(a0[i] + a1[i] + (float)xga[i]);
        unsigned hv = (unsigned)__builtin_bit_cast(
            unsigned short, (_Float16)(r * hreg[i]));
        st_dw(rh2wr + i * 512, tokhi1 | hv);
      }
      xga = xga_nx;
    } else {
      // z-waves: signal "finished reading h_t" (gates h(t+1) overwrites),
      // then stash z in LDS for waves 0,1.
      if (lane == 0) st_dw(zdone + 2 * j + (wave - 2), tok1);
#pragma unroll
      for (int i = 0; i < 4; ++i)
        z_lds[t & 1][q * 4 + i][16 * (wave - 2) + ln15] =
            sigmoid_f(a0[i] + a1[i] + (float)xga[i]);
      xga = *(const half4*)(xga_p + pn);
    }
    __syncthreads();  // z_lds handoff (the only block barrier per step)

    // ---- phase B (waves 0,1): validated rh read (token == t+1) + zdone ----
    if (wave < 2) {
      int4v elo[16], ehi[16];
      unsigned zd;
      for (;;) {
        ld16a(rh2rd, elo);
        ld16bz(rh2rd, zdp, ehi, zd);
        unsigned acc = 0;
#pragma unroll
        for (int u = 0; u < 16; ++u) {
#pragma unroll
          for (int c = 0; c < 4; ++c) {
            acc |= (((unsigned)elo[u][c]) ^ tokhi1);
            acc |= (((unsigned)ehi[u][c]) ^ tokhi1);
          }
        }
        unsigned bad = (acc >> 16) | (unsigned)(zd < tok1);
        if (__all((int)(bad == 0u))) break;
      }
      floatx4 b0 = {0.f, 0.f, 0.f, 0.f}, b1 = {0.f, 0.f, 0.f, 0.f};
#pragma unroll
      for (int kc = 0; kc < 8; kc += 2) {
        b0 = __builtin_amdgcn_mfma_f32_16x16x32_f16(
            unpk(elo[2 * kc], elo[2 * kc + 1]), wB[kc], b0, 0, 0, 0);
        b1 = __builtin_amdgcn_mfma_f32_16x16x32_f16(
            unpk(elo[2 * kc + 2], elo[2 * kc + 3]), wB[kc + 1], b1, 0, 0, 0);
      }
#pragma unroll
      for (int kc = 8; kc < 16; kc += 2) {
        b0 = __builtin_amdgcn_mfma_f32_16x16x32_f16(
            unpk(ehi[2 * (kc - 8)], ehi[2 * (kc - 8) + 1]), wB[kc], b0, 0, 0,
            0);
        b1 = __builtin_amdgcn_mfma_f32_16x16x32_f16(
            unpk(ehi[2 * (kc - 8) + 2], ehi[2 * (kc - 8) + 3]), wB[kc + 1], b1,
            0, 0, 0);
      }
      half4 xcb_nx = *(const half4*)(xcb_p + pn);
#pragma unroll
      for (int i = 0; i < 4; ++i) {
        float cv = tanh_f(b0[i] + b1[i] + (float)xcb[i]);
        float zz = z_lds[t & 1][q * 4 + i][16 * wave + ln15];
        float hn = hreg[i] + zz * (cv - hreg[i]);
        _Float16 hh = (_Float16)hn;
        hreg[i] = (float)hh;  // keep register copy == published f16 copy
        unsigned hb = (unsigned)__builtin_bit_cast(unsigned short, hh);
        st_dw(h2wr + i * 512, tokhi1 | hb);
        out[((size_t)(q * 4 + i) * S_LEN + t) * 512 + colA] = hn;
      }
      xcb = xcb_nx;
    }
    // waves 2,3 fall through to next step's validated h read (pure spin)
  }
}

__global__ void ln_kernel(float* __restrict__ out, const float* __restrict__ gamma,
                          const float* __restrict__ beta) {
  int gw = (blockIdx.x * blockDim.x + threadIdx.x) >> 6;
  int lane = threadIdx.x & 63;
  int nw = (gridDim.x * blockDim.x) >> 6;
  float4 ga = ((const float4*)(gamma + lane * 8))[0];
  float4 gb = ((const float4*)(gamma + lane * 8))[1];
  float4 ba = ((const float4*)(beta + lane * 8))[0];
  float4 bb = ((const float4*)(beta + lane * 8))[1];
  for (int r = gw; r < 16 * S_LEN; r += nw) {
    float* p = out + (size_t)r * 512 + lane * 8;
    float4 v0 = ((float4*)p)[0], v1 = ((float4*)p)[1];
    float s = v0.x + v0.y + v0.z + v0.w + v1.x + v1.y + v1.z + v1.w;
    float sq = v0.x * v0.x + v0.y * v0.y + v0.z * v0.z + v0.w * v0.w +
               v1.x * v1.x + v1.y * v1.y + v1.z * v1.z + v1.w * v1.w;
#pragma unroll
    for (int off = 32; off > 0; off >>= 1) {
      s += __shfl_xor(s, off);
      sq += __shfl_xor(sq, off);
    }
    float mean = s * (1.f / 512.f);
    float var = sq * (1.f / 512.f) - mean * mean;
    float rstd = rsqrtf(var + 1e-5f);
    v0.x = (v0.x - mean) * rstd * ga.x + ba.x;
    v0.y = (v0.y - mean) * rstd * ga.y + ba.y;
    v0.z = (v0.z - mean) * rstd * ga.z + ba.z;
    v0.w = (v0.w - mean) * rstd * ga.w + ba.w;
    v1.x = (v1.x - mean) * rstd * gb.x + bb.x;
    v1.y = (v1.y - mean) * rstd * gb.y + bb.y;
    v1.z = (v1.z - mean) * rstd * gb.z + bb.z;
    v1.w = (v1.w - mean) * rstd * gb.w + bb.w;
    ((float4*)p)[0] = v0;
    ((float4*)p)[1] = v1;
  }
}

extern "C" void kernel_launch(void* const* d_in, const int* in_sizes, int n_in,
                              void* d_out, int out_size, void* d_ws,
                              size_t ws_size, hipStream_t stream) {
  const float* points = (const float*)d_in[0];
  const float* W_gate = (const float*)d_in[1];
  const float* b_gate = (const float*)d_in[2];
  const float* W_cand = (const float*)d_in[3];
  const float* b_cand = (const float*)d_in[4];
  const float* gamma = (const float*)d_in[5];
  const float* beta = (const float*)d_in[6];
  char* ws = (char*)d_ws;
  _Float16* Whpk = (_Float16*)(ws + OFF_WHPK);
  _Float16* Wxpk = (_Float16*)(ws + OFF_WXPK);
  unsigned* h2 = (unsigned*)(ws + OFF_HBUF);
  unsigned* zdone = (unsigned*)(ws + OFF_CNT);
  unsigned* rh2 = (unsigned*)(ws + OFF_RH);
  _Float16* xgt = (_Float16*)(ws + OFF_XGT);
  float* out = (float*)d_out;

  // zero h2 (token 0 == h_0 = 0) + zdone + rh2 (token 0 = never-valid)
  hipMemsetAsync(ws + OFF_HBUF, 0, 81920, stream);
  pack_kernel<<<768, 256, 0, stream>>>(W_gate, W_cand, Whpk, Wxpk);
  xgemm_kernel<<<S_LEN, TPB, 0, stream>>>(points, b_gate, b_cand, Wxpk, xgt);
  rec_kernel<<<NBLK, TPB, 0, stream>>>(Whpk, xgt, h2, rh2, zdone, out);
  ln_kernel<<<512, 256, 0, stream>>>(out, gamma, beta);
}

// Round 6
// 12589.082 us; speedup vs baseline: 2.6740x; 2.6740x over previous
//
#include <hip/hip_runtime.h>

// GeodesicStateBlock: GRU-style scan (B=16,S=2048,D=512) + LayerNorm.
// Identity: deformed = points + (states - points) = states, so out = LN(states).
//
// Round-9 = round-8's token protocol + round-5's cooperative staging.
//  - h and r*h exchanged as packed dwords (token<<16)|f16_bits. Aligned 4B
//    accesses are single-copy atomic => every dword self-validates. No
//    producer drains, no flags, no barriers between blocks; the consumer's
//    validation IS the synchronization (protocol proven correct in round-8).
//  - Cooperative staging (round-5): each wave loads only ITS 4 fragments
//    (8 dwordx4, 128 B/lane), validates, retries only its own slice with a
//    128-cy s_sleep backoff, unpacks (v_perm), writes f16 to LDS. 4x less
//    LLC traffic than round-8, and retries are 4x cheaper.
//  - Double-buffered LDS stage => only 2 __syncthreads per step (syncA /
//    syncB); buffer-reuse safety follows from program order around them.
//  - Deadlock/WAR chain (round-8's, zdone replaced by intra-block syncs):
//    block k publishes rh(t+1) only after syncA(t) (=> all 4 of its waves
//    finished reading h(t)), so h(t+1) stores (gated on full rh(t+1)
//    staging) cannot overwrite h(t) early. Block k stores h(t+1) only after
//    syncB(t) (=> all its waves finished reading rh(t+1)), so rh(t+2)
//    stores (gated on full h(t+1) staging) cannot overwrite rh(t+1) early.
//    Tokens are compared for EQUALITY; the chain makes stale-future
//    impossible, t+1 <= 2048 << 65536 so no wraparound.

typedef _Float16 half8 __attribute__((ext_vector_type(8)));
typedef _Float16 half4 __attribute__((ext_vector_type(4)));
typedef float floatx4 __attribute__((ext_vector_type(4)));
typedef int int4v __attribute__((ext_vector_type(4)));

#define NBLK 16
#define TPB 256
#define S_LEN 2048

// ws layout (bytes)
#define SZ_WPK (96ull * 16 * 64 * 8 * 2)  // 1,572,864 (96 tiles x 16 KB)
#define OFF_WHPK 0ull
#define OFF_WXPK (OFF_WHPK + SZ_WPK)
#define OFF_HBUF (OFF_WXPK + SZ_WPK)    // 32 KB: h2[16][512] dwords (zeroed)
#define OFF_RH (OFF_HBUF + 32768ull)    // 32 KB: rh2[16][512] dwords (zeroed)
#define OFF_XGT (OFF_RH + 32768ull)     // 2048*96*256*2 = 100,663,296 B

__device__ __forceinline__ float sigmoid_f(float x) {
  return 1.f / (1.f + __expf(-x));
}
__device__ __forceinline__ float tanh_f(float x) {
  x = fminf(15.f, fmaxf(-15.f, x));
  float e = __expf(2.f * x);
  return (e - 1.f) / (e + 1.f);
}

// ---- LLC-coherent (sc0 sc1) ops ----
// One wave's 4 fragments = 8 dwordx4 (frag u at byte u*128 + {0,16}) + drain,
// in ONE asm block so no use can be scheduled before the waitcnt.
__device__ __forceinline__ void ld8_cg(const unsigned* p, int4v (&d)[8]) {
  asm volatile(
      "global_load_dwordx4 %0, %8, off sc0 sc1\n\t"
      "global_load_dwordx4 %1, %8, off offset:16 sc0 sc1\n\t"
      "global_load_dwordx4 %2, %8, off offset:128 sc0 sc1\n\t"
      "global_load_dwordx4 %3, %8, off offset:144 sc0 sc1\n\t"
      "global_load_dwordx4 %4, %8, off offset:256 sc0 sc1\n\t"
      "global_load_dwordx4 %5, %8, off offset:272 sc0 sc1\n\t"
      "global_load_dwordx4 %6, %8, off offset:384 sc0 sc1\n\t"
      "global_load_dwordx4 %7, %8, off offset:400 sc0 sc1\n\t"
      "s_waitcnt vmcnt(0)"
      : "=&v"(d[0]), "=&v"(d[1]), "=&v"(d[2]), "=&v"(d[3]), "=&v"(d[4]),
        "=&v"(d[5]), "=&v"(d[6]), "=&v"(d[7])
      : "v"(p)
      : "memory");
}
__device__ __forceinline__ void st_dw(unsigned* p, unsigned v) {
  asm volatile("global_store_dword %0, %1, off sc0 sc1" ::"v"(p), "v"(v)
               : "memory");
}
// pack low16 of (p0,p1) -> one dword (p0 low, p1 high)
__device__ __forceinline__ unsigned pk2(unsigned p1, unsigned p0) {
  return __builtin_amdgcn_perm(p1, p0, 0x05040100u);
}

// Validated cooperative stage: spin until this wave's 4 fragments all carry
// `tokhi`, then unpack payloads to LDS (stride 64 int4v between fragments).
__device__ __forceinline__ void stage_val(const unsigned* p, unsigned tokhi,
                                          int4v* lds_dst) {
  int4v d[8];
  for (;;) {
    ld8_cg(p, d);
    unsigned acc = 0;
#pragma unroll
    for (int u = 0; u < 8; ++u)
#pragma unroll
      for (int c = 0; c < 4; ++c) acc |= ((unsigned)d[u][c]) ^ tokhi;
    if (__all((int)((acc >> 16) == 0u))) break;
    __builtin_amdgcn_s_sleep(2);  // ~128 cy backoff: cap retry LLC pressure
  }
#pragma unroll
  for (int u = 0; u < 4; ++u) {
    int4v f;
    f[0] = (int)pk2((unsigned)d[2 * u][1], (unsigned)d[2 * u][0]);
    f[1] = (int)pk2((unsigned)d[2 * u][3], (unsigned)d[2 * u][2]);
    f[2] = (int)pk2((unsigned)d[2 * u + 1][1], (unsigned)d[2 * u + 1][0]);
    f[3] = (int)pk2((unsigned)d[2 * u + 1][3], (unsigned)d[2 * u + 1][2]);
    lds_dst[u * 64] = f;
  }
}

// ---- pack weights into MFMA B-fragment order ----
// Whpk/Wxpk: [96 tiles][16 kc][64 lanes][8 f16]; tiles 0..63 gate, 64..95 cand.
// B-frag: lane holds B[k = kc*32 + (lane>>4)*8 + jj][n = lane&15].
__global__ void pack_kernel(const float* __restrict__ Wg,
                            const float* __restrict__ Wc,
                            _Float16* __restrict__ Whpk,
                            _Float16* __restrict__ Wxpk) {
  int unit = blockIdx.x * 4 + (threadIdx.x >> 6);  // 0..3071
  int lane = threadIdx.x & 63;
  int set = (unit >= 1536) ? 1 : 0;  // 0: h-part (rows 512+), 1: x-part
  int rem = unit - set * 1536;
  int tile = rem >> 4, kc = rem & 15;
  int kb = kc * 32 + ((lane >> 4) << 3);
  int n = lane & 15;
  int row0 = set ? 0 : 512;
  half8 w;
  if (tile < 64) {
    int col = tile * 16 + n;
#pragma unroll
    for (int jj = 0; jj < 8; ++jj)
      w[jj] = (_Float16)Wg[(size_t)(row0 + kb + jj) * 1024 + col];
  } else {
    int col = (tile - 64) * 16 + n;
#pragma unroll
    for (int jj = 0; jj < 8; ++jj)
      w[jj] = (_Float16)Wc[(size_t)(row0 + kb + jj) * 512 + col];
  }
  _Float16* dst = set ? Wxpk : Whpk;
  *(half8*)(dst + ((size_t)rem * 64 + lane) * 8) = w;
}

// ---- XGT = points @ W_x + bias, all steps; layout [t][tile][c16][b16] ----
__global__ __launch_bounds__(TPB) void xgemm_kernel(
    const float* __restrict__ points, const float* __restrict__ b_gate,
    const float* __restrict__ b_cand, const _Float16* __restrict__ Wxpk,
    _Float16* __restrict__ xgt) {
  __shared__ _Float16 x_lds[16][520];
  const int tid = threadIdx.x;
  const int wave = tid >> 6, lane = tid & 63;
  const int ln15 = lane & 15, q = lane >> 4;
  const int t = blockIdx.x;
  const int m = tid & 15, ch = tid >> 4;

  // stage x_t (f32 -> f16)
  const float* xp = points + ((size_t)m * S_LEN + t) * 512 + ch * 32;
#pragma unroll
  for (int u = 0; u < 4; ++u) {
    float4 f0 = ((const float4*)xp)[2 * u];
    float4 f1 = ((const float4*)xp)[2 * u + 1];
    half8 hv;
    hv[0] = (_Float16)f0.x; hv[1] = (_Float16)f0.y;
    hv[2] = (_Float16)f0.z; hv[3] = (_Float16)f0.w;
    hv[4] = (_Float16)f1.x; hv[5] = (_Float16)f1.y;
    hv[6] = (_Float16)f1.z; hv[7] = (_Float16)f1.w;
    *(half8*)&x_lds[m][ch * 32 + u * 8] = hv;
  }
  __syncthreads();

  for (int tile = wave; tile < 96; tile += 4) {
    const _Float16* W = Wxpk + (size_t)tile * 8192;
    floatx4 a0 = {0.f, 0.f, 0.f, 0.f}, a1 = {0.f, 0.f, 0.f, 0.f};
#pragma unroll
    for (int kc = 0; kc < 16; kc += 2) {
      a0 = __builtin_amdgcn_mfma_f32_16x16x32_f16(
          *(const half8*)&x_lds[ln15][kc * 32 + q * 8],
          *(const half8*)(W + ((size_t)kc * 64 + lane) * 8), a0, 0, 0, 0);
      a1 = __builtin_amdgcn_mfma_f32_16x16x32_f16(
          *(const half8*)&x_lds[ln15][(kc + 1) * 32 + q * 8],
          *(const half8*)(W + ((size_t)(kc + 1) * 64 + lane) * 8), a1, 0, 0, 0);
    }
    float bias = (tile < 64) ? b_gate[tile * 16 + ln15]
                             : b_cand[(tile - 64) * 16 + ln15];
    half4 o;
#pragma unroll
    for (int i = 0; i < 4; ++i) o[i] = (_Float16)(a0[i] + a1[i] + bias);
    *(half4*)(xgt + (((size_t)t * 96 + tile) * 16 + ln15) * 16 + q * 4) = o;
  }
}

// ---- serial recurrence: 16 persistent blocks, register-resident weights ----
__global__ __launch_bounds__(TPB, 1) void rec_kernel(
    const _Float16* __restrict__ Whpk, const _Float16* __restrict__ xgt,
    unsigned* __restrict__ h2, unsigned* __restrict__ rh2,
    float* __restrict__ out) {
  __shared__ int4v hsh[2][1024];  // 32 KB: double-buffered f16 fragment stage
  __shared__ float z_lds[16][36];

  const int tid = threadIdx.x;
  const int wave = tid >> 6, lane = tid & 63;
  const int ln15 = lane & 15, q = lane >> 4;
  const int j = blockIdx.x;

  // wave -> tiles: waves 0,1 gate-r tiles 2j,2j+1 (cols 32j..32j+31) + cand
  // tiles 64+2j,65+2j; waves 2,3 gate-z tiles 32+2j,33+2j.
  const int twA = (wave < 2) ? (2 * j + wave) : (32 + 2 * j + (wave - 2));
  const int twB = 64 + 2 * j + (wave & 1);
  const int colA = 32 * j + 16 * (wave & 1) + ln15;

  // weights -> registers (tile stride 8192 f16; kc stride 512 f16)
  half8 wA[16], wB[16];
  {
    const _Float16* sA = Whpk + (size_t)twA * 8192 + lane * 8;
#pragma unroll
    for (int kc = 0; kc < 16; ++kc) wA[kc] = *(const half8*)(sA + kc * 512);
  }
  if (wave < 2) {
    const _Float16* sB = Whpk + (size_t)twB * 8192 + lane * 8;
#pragma unroll
    for (int kc = 0; kc < 16; ++kc) wB[kc] = *(const half8*)(sB + kc * 512);
  }

  // cooperative staging: wave w owns fragments kc=4w..4w+3.
  const unsigned* h2rd = h2 + ln15 * 512 + q * 8 + wave * 128;
  const unsigned* rh2rd = rh2 + ln15 * 512 + q * 8 + wave * 128;
  unsigned* rh2wr = rh2 + (q * 4) * 512 + colA;  // + i*512
  unsigned* h2wr = h2 + (q * 4) * 512 + colA;    // + i*512
  int4v* ldsA = &hsh[0][(4 * wave) * 64 + lane];
  int4v* ldsB = &hsh[1][(4 * wave) * 64 + lane];

  // xgt operand pointers; per-t stride = 96*16*16 = 24576 f16.
  const _Float16* xga_p = xgt + ((size_t)twA * 16 + ln15) * 16 + q * 4;
  const _Float16* xcb_p = xgt + ((size_t)twB * 16 + ln15) * 16 + q * 4;
  half4 xga = *(const half4*)xga_p;
  half4 xcb = {0, 0, 0, 0};
  if (wave < 2) xcb = *(const half4*)xcb_p;

  float hreg[4] = {0.f, 0.f, 0.f, 0.f};  // h[q*4+i][colA] (waves 0-1)

  for (int t = 0; t < S_LEN; ++t) {
    const size_t pn = (size_t)((t + 1 < S_LEN) ? t + 1 : t) * 24576;
    const unsigned tok1 = (unsigned)t + 1u;
    const unsigned tokhi1 = tok1 << 16;

    // ---- phase A: co-op validated h@t stage (token == t) ----
    stage_val(h2rd, ((unsigned)t) << 16, ldsA);
    __syncthreads();  // syncA: hsh[0] fully staged; all h@t reads done

    floatx4 a0 = {0.f, 0.f, 0.f, 0.f}, a1 = {0.f, 0.f, 0.f, 0.f};
#pragma unroll
    for (int kc = 0; kc < 16; kc += 2) {
      a0 = __builtin_amdgcn_mfma_f32_16x16x32_f16(
          *(const half8*)&hsh[0][kc * 64 + lane], wA[kc], a0, 0, 0, 0);
      a1 = __builtin_amdgcn_mfma_f32_16x16x32_f16(
          *(const half8*)&hsh[0][(kc + 1) * 64 + lane], wA[kc + 1], a1, 0, 0,
          0);
    }
    if (wave < 2) {  // r-cols: publish r*h token-dwords (no drain, no flag)
      half4 xga_nx = *(const half4*)(xga_p + pn);
#pragma unroll
      for (int i = 0; i < 4; ++i) {
        float r = sigmoid_f(a0[i] + a1[i] + (float)xga[i]);
        unsigned hv = (unsigned)__builtin_bit_cast(unsigned short,
                                                   (_Float16)(r * hreg[i]));
        st_dw(rh2wr + i * 512, tokhi1 | hv);
      }
      xga = xga_nx;
    } else {  // z-cols -> LDS (single buffer safe: see sync analysis)
#pragma unroll
      for (int i = 0; i < 4; ++i)
        z_lds[q * 4 + i][16 * (wave - 2) + ln15] =
            sigmoid_f(a0[i] + a1[i] + (float)xga[i]);
      xga = *(const half4*)(xga_p + pn);
    }

    // ---- phase B: co-op validated rh@t+1 stage (token == t+1) ----
    stage_val(rh2rd, tokhi1, ldsB);
    __syncthreads();  // syncB: hsh[1] staged; all rh@t+1 reads done

    if (wave < 2) {
      floatx4 b0 = {0.f, 0.f, 0.f, 0.f}, b1 = {0.f, 0.f, 0.f, 0.f};
#pragma unroll
      for (int kc = 0; kc < 16; kc += 2) {
        b0 = __builtin_amdgcn_mfma_f32_16x16x32_f16(
            *(const half8*)&hsh[1][kc * 64 + lane], wB[kc], b0, 0, 0, 0);
        b1 = __builtin_amdgcn_mfma_f32_16x16x32_f16(
            *(const half8*)&hsh[1][(kc + 1) * 64 + lane], wB[kc + 1], b1, 0, 0,
            0);
      }
      half4 xcb_nx = *(const half4*)(xcb_p + pn);
#pragma unroll
      for (int i = 0; i < 4; ++i) {
        float cv = tanh_f(b0[i] + b1[i] + (float)xcb[i]);
        float zz = z_lds[q * 4 + i][16 * wave + ln15];
        float hn = hreg[i] + zz * (cv - hreg[i]);
        _Float16 hh = (_Float16)hn;
        hreg[i] = (float)hh;  // keep register copy == published f16 copy
        unsigned hb = (unsigned)__builtin_bit_cast(unsigned short, hh);
        st_dw(h2wr + i * 512, tokhi1 | hb);
        out[((size_t)(q * 4 + i) * S_LEN + t) * 512 + colA] = hn;
      }
      xcb = xcb_nx;
    }
    // waves 2,3 fall through to next step's validated h stage
  }
}

__global__ void ln_kernel(float* __restrict__ out, const float* __restrict__ gamma,
                          const float* __restrict__ beta) {
  int gw = (blockIdx.x * blockDim.x + threadIdx.x) >> 6;
  int lane = threadIdx.x & 63;
  int nw = (gridDim.x * blockDim.x) >> 6;
  float4 ga = ((const float4*)(gamma + lane * 8))[0];
  float4 gb = ((const float4*)(gamma + lane * 8))[1];
  float4 ba = ((const float4*)(beta + lane * 8))[0];
  float4 bb = ((const float4*)(beta + lane * 8))[1];
  for (int r = gw; r < 16 * S_LEN; r += nw) {
    float* p = out + (size_t)r * 512 + lane * 8;
    float4 v0 = ((float4*)p)[0], v1 = ((float4*)p)[1];
    float s = v0.x + v0.y + v0.z + v0.w + v1.x + v1.y + v1.z + v1.w;
    float sq = v0.x * v0.x + v0.y * v0.y + v0.z * v0.z + v0.w * v0.w +
               v1.x * v1.x + v1.y * v1.y + v1.z * v1.z + v1.w * v1.w;
#pragma unroll
    for (int off = 32; off > 0; off >>= 1) {
      s += __shfl_xor(s, off);
      sq += __shfl_xor(sq, off);
    }
    float mean = s * (1.f / 512.f);
    float var = sq * (1.f / 512.f) - mean * mean;
    float rstd = rsqrtf(var + 1e-5f);
    v0.x = (v0.x - mean) * rstd * ga.x + ba.x;
    v0.y = (v0.y - mean) * rstd * ga.y + ba.y;
    v0.z = (v0.z - mean) * rstd * ga.z + ba.z;
    v0.w = (v0.w - mean) * rstd * ga.w + ba.w;
    v1.x = (v1.x - mean) * rstd * gb.x + bb.x;
    v1.y = (v1.y - mean) * rstd * gb.y + bb.y;
    v1.z = (v1.z - mean) * rstd * gb.z + bb.z;
    v1.w = (v1.w - mean) * rstd * gb.w + bb.w;
    ((float4*)p)[0] = v0;
    ((float4*)p)[1] = v1;
  }
}

extern "C" void kernel_launch(void* const* d_in, const int* in_sizes, int n_in,
                              void* d_out, int out_size, void* d_ws,
                              size_t ws_size, hipStream_t stream) {
  const float* points = (const float*)d_in[0];
  const float* W_gate = (const float*)d_in[1];
  const float* b_gate = (const float*)d_in[2];
  const float* W_cand = (const float*)d_in[3];
  const float* b_cand = (const float*)d_in[4];
  const float* gamma = (const float*)d_in[5];
  const float* beta = (const float*)d_in[6];
  char* ws = (char*)d_ws;
  _Float16* Whpk = (_Float16*)(ws + OFF_WHPK);
  _Float16* Wxpk = (_Float16*)(ws + OFF_WXPK);
  unsigned* h2 = (unsigned*)(ws + OFF_HBUF);
  unsigned* rh2 = (unsigned*)(ws + OFF_RH);
  _Float16* xgt = (_Float16*)(ws + OFF_XGT);
  float* out = (float*)d_out;

  // zero h2 (token 0 == h_0 = 0) + rh2 (token 0 = never-valid)
  hipMemsetAsync(ws + OFF_HBUF, 0, 65536, stream);
  pack_kernel<<<768, 256, 0, stream>>>(W_gate, W_cand, Whpk, Wxpk);
  xgemm_kernel<<<S_LEN, TPB, 0, stream>>>(points, b_gate, b_cand, Wxpk, xgt);
  rec_kernel<<<NBLK, TPB, 0, stream>>>(Whpk, xgt, h2, rh2, out);
  ln_kernel<<<512, 256, 0, stream>>>(out, gamma, beta);
}